// Round 9
// baseline (50.997 us; speedup 1.0000x reference)
//
#include <hip/hip_runtime.h>
#include <math.h>

#define OUT 14
#define RATIO 2
#define NS (OUT*RATIO)      // 28 sample positions per axis
#define NPIX (OUT*OUT)      // 196
#define C_TOT 256
#define CG 4                // channels per block (float4 interleave)
#define NBOX_PER_B 128
#define NTHREADS 256
#define PATCH_CAP 1536      // float4 slots; worst aligned patch <= ~1470
#define NROI 256

// ---- workspace layout ----
#define META_INTS 8
#define META_OFF  0
#define IDX_OFF   (NROI*META_INTS*4)                 // int4 [256][196]
#define WY_OFF    (IDX_OFF + NROI*NPIX*16)           // float4 [256][196] (fy * 0.25)
#define WX_OFF    (WY_OFF  + NROI*NPIX*16)           // float4 [256][196] (fx raw)
#define WS_NEEDED (WX_OFF  + NROI*NPIX*16)           // ~2.42 MB

// =====================================================================
// Setup kernel: one block per roi. Patch columns are aligned down to
// even (xa = xmin & ~1) so levels 0-2 can stage with float2 loads.
// Records hold prebaked slot offsets: iv = {ry0*nca, ry1*nca, cx0, cx1}
// (relative to ymin/xa), weights wy*0.25 / wx.
// =====================================================================
__global__ __launch_bounds__(NTHREADS)
void roi_setup_kernel(const float* __restrict__ boxes,
                      int*    __restrict__ metaW,
                      int4*   __restrict__ idxW,
                      float4* __restrict__ wyW,
                      float4* __restrict__ wxW)
{
    const int k   = blockIdx.x;
    const int tid = threadIdx.x;

    __shared__ int   s_ylo[NS], s_xlo[NS];
    __shared__ float s_fyh[NS], s_fyl[NS], s_fxh[NS], s_fxl[NS];

    const float bx1 = boxes[k*4+0];
    const float by1 = boxes[k*4+1];
    const float bx2 = boxes[k*4+2];
    const float by2 = boxes[k*4+3];

    const float wbox = bx2 - bx1;
    const float hbox = by2 - by1;
    const float sdim = sqrtf(wbox * hbox);
    float lvlf = floorf(4.0f + log2f(sdim / 224.0f + 1e-6f));
    lvlf = fminf(fmaxf(lvlf, 2.0f), 5.0f);
    const int lidx = (int)lvlf - 2;   // 0..3

    int H, W;
    float scale;
    if      (lidx == 0) { H = 200; W = 200; scale = 0.25f;    }
    else if (lidx == 1) { H = 100; W = 100; scale = 0.125f;   }
    else if (lidx == 2) { H = 50;  W = 50;  scale = 0.0625f;  }
    else                { H = 25;  W = 25;  scale = 0.03125f; }

    const float x1 = bx1 * scale;
    const float y1 = by1 * scale;
    const float x2 = bx2 * scale;
    const float y2 = by2 * scale;
    const float rw = fmaxf(x2 - x1, 1.0f);
    const float rh = fmaxf(y2 - y1, 1.0f);
    const float bw = rw / (float)OUT;
    const float bh = rh / (float)OUT;

    if (tid < NS) {
        const int i = tid;
        const float off = ((float)i + 0.5f) / (float)RATIO;
        {
            const float c  = y1 + bh * off;
            const bool  v  = (c > -1.0f) && (c < (float)H);
            const float cc = fminf(fmaxf(c, 0.0f), (float)(H - 1));
            const float fl = fminf(fmaxf(floorf(cc), 0.0f), (float)(H - 2));
            const float fr = cc - fl;
            s_ylo[i] = (int)fl;
            s_fyl[i] = v ? fr         : 0.0f;
            s_fyh[i] = v ? 1.0f - fr  : 0.0f;
        }
        {
            const float c  = x1 + bw * off;
            const bool  v  = (c > -1.0f) && (c < (float)W);
            const float cc = fminf(fmaxf(c, 0.0f), (float)(W - 1));
            const float fl = fminf(fmaxf(floorf(cc), 0.0f), (float)(W - 2));
            const float fr = cc - fl;
            s_xlo[i] = (int)fl;
            s_fxl[i] = v ? fr         : 0.0f;
            s_fxh[i] = v ? 1.0f - fr  : 0.0f;
        }
    }
    __syncthreads();

    const int ymin  = s_ylo[0];
    const int xmin  = s_xlo[0];
    const int nrows = s_ylo[NS-1] + 2 - ymin;
    const int ncols = s_xlo[NS-1] + 2 - xmin;
    const int o     = xmin & 1;
    const int xa    = xmin - o;
    const int nca   = (o + ncols + 1) & ~1;   // even width, <= ncols+2
    const int nqr   = nca >> 1;               // float2 quads per row

    if (tid == 0) {
        int* m = metaW + k*META_INTS;
        m[0] = lidx;
        m[1] = ymin;
        m[2] = xa;
        m[3] = nrows;
        m[4] = nca;
        m[5] = nqr;
        m[6] = __float_as_int(1.0f / (float)nqr);
        m[7] = __float_as_int(1.0f / (float)nca);
    }

    if (tid < NPIX) {
        const int ph = tid / OUT;
        const int pw = tid - ph * OUT;
        const int sy0 = 2*ph, sy1 = 2*ph + 1;
        const int sx0 = 2*pw, sx1 = 2*pw + 1;
        int4 iv;
        iv.x = (s_ylo[sy0] - ymin) * nca;   // row base 0 (slot units)
        iv.y = (s_ylo[sy1] - ymin) * nca;   // row base 1
        iv.z =  s_xlo[sx0] - xa;            // col base 0
        iv.w =  s_xlo[sx1] - xa;            // col base 1
        idxW[k*NPIX + tid] = iv;
        float4 wy;   // 0.25 sample-average folded into y weights
        wy.x = s_fyh[sy0] * 0.25f;
        wy.y = s_fyl[sy0] * 0.25f;
        wy.z = s_fyh[sy1] * 0.25f;
        wy.w = s_fyl[sy1] * 0.25f;
        float4 wx;
        wx.x = s_fxh[sx0];
        wx.y = s_fxl[sx0];
        wx.z = s_fxh[sx1];
        wx.w = s_fxl[sx1];
        wyW[k*NPIX + tid] = wy;
        wxW[k*NPIX + tid] = wx;
    }
}

// =====================================================================
// Main kernel: grid (64 groups, 256 rois). Levels 0-2 stage with
// float2 global loads (8B-aligned by construction: W and plane strides
// even in dwords, xa even), channel-in-lane split (lanes 0-3 = 4
// channels of one quad) -> interleaved-LDS b32 writes at 4-way
// conflict, 4x fewer vmem instrs. Level 3 (W=25, odd strides) keeps
// the scalar staging path. Compute epilogue identical to R5.
// =====================================================================
__global__ __launch_bounds__(NTHREADS)
void roi_align_v2_kernel(const float* __restrict__ f0,
                         const float* __restrict__ f1,
                         const float* __restrict__ f2,
                         const float* __restrict__ f3,
                         const int*    __restrict__ metaW,
                         const int4*   __restrict__ idxW,
                         const float4* __restrict__ wyW,
                         const float4* __restrict__ wxW,
                         float* __restrict__ out)
{
    const int cg  = blockIdx.x;   // channel group, 0..63
    const int k   = blockIdx.y;   // roi, 0..255
    const int tid = threadIdx.x;

    __shared__ float4 s_patch[PATCH_CAP];   // 24576 B
    float* s_f = (float*)s_patch;

    // ---- per-pixel records (issued first; independent of meta) ----
    const bool active = (tid < NPIX);
    int4   iv = {0,0,0,0};
    float4 wy = {0,0,0,0};
    float4 wx = {0,0,0,0};
    if (active) {
        iv = idxW[k*NPIX + tid];
        wy = wyW[k*NPIX + tid];
        wx = wxW[k*NPIX + tid];
    }

    // ---- uniform meta (scalar loads) ----
    const int* m = metaW + k*META_INTS;
    const int lidx    = m[0];
    const int ymin    = m[1];
    const int xa      = m[2];
    const int nrows   = m[3];
    const int nca     = m[4];
    const int nqr     = m[5];
    const float rcpq  = __int_as_float(m[6]);
    const float rcpc  = __int_as_float(m[7]);

    const float* fptr;
    int W;
    if      (lidx == 0) { fptr = f0; W = 200; }
    else if (lidx == 1) { fptr = f1; W = 100; }
    else if (lidx == 2) { fptr = f2; W = 50;  }
    else                { fptr = f3; W = 25;  }
    const size_t plane = (size_t)W * (size_t)W;

    const float* fbase = fptr
        + ((size_t)(k / NBOX_PER_B) * C_TOT + (size_t)cg * CG) * plane
        + (size_t)ymin * W + xa;

    if (lidx != 3) {
        // ---- float2 staging, channel-in-lane ----
        const int NQ2 = nrows * nqr;
        const int tot = NQ2 * 4;
        for (int t = tid; t < tot; t += NTHREADS) {
            const int ch = t & 3;
            const int u  = t >> 2;
            const int r  = (int)(((float)u + 0.5f) * rcpq);   // u / nqr
            const int qc = u - r * nqr;
            const int gcol = xa + 2*qc;
            const int slot = r * nca + 2*qc;
            const float* g = fbase + (size_t)ch * plane + (size_t)r * W + 2*qc;
            if (gcol + 1 < W) {
                const float2 v = *(const float2*)g;
                if (slot + 1 < PATCH_CAP) {
                    s_f[slot*4 + ch]     = v.x;
                    s_f[slot*4 + 4 + ch] = v.y;
                }
            } else if (gcol < W) {
                if (slot < PATCH_CAP) s_f[slot*4 + ch] = *g;
            }
        }
    } else {
        // ---- level-3 scalar staging (odd strides; tiny patches) ----
        const int nelem2 = nrows * nca;
        const float* g0 = fbase;
        const float* g1 = fbase +   plane;
        const float* g2 = fbase + 2*plane;
        const float* g3 = fbase + 3*plane;
        for (int i = tid; i < nelem2; i += NTHREADS) {
            const int r  = (int)(((float)i + 0.5f) * rcpc);   // i / nca
            const int cc = i - r * nca;
            if (xa + cc < W && i < PATCH_CAP) {
                const int go = r * W + cc;
                float4 v;
                v.x = g0[go]; v.y = g1[go]; v.z = g2[go]; v.w = g3[go];
                s_patch[i] = v;
            }
        }
    }
    __syncthreads();

    // ---- bilinear: 16 x ds_read_b128, 64 FMA per pixel (4 channels) ----
    if (active) {
        float4 acc = {0.0f, 0.0f, 0.0f, 0.0f};
        #pragma unroll
        for (int ys = 0; ys < 2; ++ys) {
            const int   rb = ys ? iv.y : iv.x;
            const float yh = ys ? wy.z : wy.x;
            const float yl = ys ? wy.w : wy.y;
            #pragma unroll
            for (int xs = 0; xs < 2; ++xs) {
                const int base = rb + (xs ? iv.w : iv.z);
                const float xh = xs ? wx.z : wx.x;
                const float xl = xs ? wx.w : wx.y;
                const float w00 = yh*xh, w01 = yh*xl, w10 = yl*xh, w11 = yl*xl;
                const float4 v00 = s_patch[base];
                const float4 v01 = s_patch[base + 1];
                const float4 v10 = s_patch[base + nca];
                const float4 v11 = s_patch[base + nca + 1];
                acc.x += w00*v00.x + w01*v01.x + w10*v10.x + w11*v11.x;
                acc.y += w00*v00.y + w01*v01.y + w10*v10.y + w11*v11.y;
                acc.z += w00*v00.z + w01*v01.z + w10*v10.z + w11*v11.z;
                acc.w += w00*v00.w + w01*v01.w + w10*v10.w + w11*v11.w;
            }
        }
        float* ob = out + ((size_t)k * C_TOT + (size_t)cg * CG) * NPIX + tid;
        ob[0*NPIX] = acc.x;
        ob[1*NPIX] = acc.y;
        ob[2*NPIX] = acc.z;
        ob[3*NPIX] = acc.w;
    }
}

// =====================================================================
// Fallback: self-contained monolithic kernel (used only if ws too small)
// =====================================================================
__global__ __launch_bounds__(NTHREADS)
void roi_align_fpn_kernel(const float* __restrict__ f0,
                          const float* __restrict__ f1,
                          const float* __restrict__ f2,
                          const float* __restrict__ f3,
                          const float* __restrict__ boxes,
                          float* __restrict__ out)
{
    const int k   = blockIdx.x;
    const int cg  = blockIdx.y;
    const int tid = threadIdx.x;

    __shared__ float4 s_patch[1280];
    __shared__ int   s_ylo[NS], s_xlo[NS];
    __shared__ float s_fyh[NS], s_fyl[NS], s_fxh[NS], s_fxl[NS];

    const float bx1 = boxes[k*4+0];
    const float by1 = boxes[k*4+1];
    const float bx2 = boxes[k*4+2];
    const float by2 = boxes[k*4+3];

    const float wbox = bx2 - bx1;
    const float hbox = by2 - by1;
    const float sdim = sqrtf(wbox * hbox);
    float lvlf = floorf(4.0f + log2f(sdim / 224.0f + 1e-6f));
    lvlf = fminf(fmaxf(lvlf, 2.0f), 5.0f);
    const int lidx = (int)lvlf - 2;

    const float* fptr;
    int H, W;
    float scale;
    if      (lidx == 0) { fptr = f0; H = 200; W = 200; scale = 0.25f;    }
    else if (lidx == 1) { fptr = f1; H = 100; W = 100; scale = 0.125f;   }
    else if (lidx == 2) { fptr = f2; H = 50;  W = 50;  scale = 0.0625f;  }
    else                { fptr = f3; H = 25;  W = 25;  scale = 0.03125f; }

    const float x1 = bx1 * scale;
    const float y1 = by1 * scale;
    const float x2 = bx2 * scale;
    const float y2 = by2 * scale;
    const float rw = fmaxf(x2 - x1, 1.0f);
    const float rh = fmaxf(y2 - y1, 1.0f);
    const float bw = rw / (float)OUT;
    const float bh = rh / (float)OUT;

    if (tid < NS) {
        const int i = tid;
        const float off = ((float)i + 0.5f) / (float)RATIO;
        {
            const float c  = y1 + bh * off;
            const bool  v  = (c > -1.0f) && (c < (float)H);
            const float cc = fminf(fmaxf(c, 0.0f), (float)(H - 1));
            const float fl = fminf(fmaxf(floorf(cc), 0.0f), (float)(H - 2));
            const float fr = cc - fl;
            s_ylo[i] = (int)fl;
            s_fyl[i] = v ? fr         : 0.0f;
            s_fyh[i] = v ? 1.0f - fr  : 0.0f;
        }
        {
            const float c  = x1 + bw * off;
            const bool  v  = (c > -1.0f) && (c < (float)W);
            const float cc = fminf(fmaxf(c, 0.0f), (float)(W - 1));
            const float fl = fminf(fmaxf(floorf(cc), 0.0f), (float)(W - 2));
            const float fr = cc - fl;
            s_xlo[i] = (int)fl;
            s_fxl[i] = v ? fr         : 0.0f;
            s_fxh[i] = v ? 1.0f - fr  : 0.0f;
        }
    }
    __syncthreads();

    const int ymin  = s_ylo[0];
    const int xmin  = s_xlo[0];
    const int nrows = s_ylo[NS-1] + 2 - ymin;
    const int ncols = s_xlo[NS-1] + 2 - xmin;
    const int padded = ncols | 1;
    const int stridep = (nrows * padded <= 1280) ? padded : ncols;
    const int nelem = nrows * ncols;
    const float rcpc = 1.0f / (float)ncols;

    const bool active = (tid < NPIX);
    int rb0 = 0, rb1 = 0, cbase0 = 0, cbase1 = 0;
    float wt[16];
    #pragma unroll
    for (int i = 0; i < 16; ++i) wt[i] = 0.0f;
    if (active) {
        const int ph = tid / OUT;
        const int pw = tid - ph * OUT;
        const int sy0 = 2*ph, sy1 = 2*ph + 1;
        const int sx0 = 2*pw, sx1 = 2*pw + 1;
        rb0 = (s_ylo[sy0] - ymin) * stridep;
        rb1 = (s_ylo[sy1] - ymin) * stridep;
        cbase0 = s_xlo[sx0] - xmin;
        cbase1 = s_xlo[sx1] - xmin;
        const float fyh_[2] = { s_fyh[sy0], s_fyh[sy1] };
        const float fyl_[2] = { s_fyl[sy0], s_fyl[sy1] };
        const float fxh_[2] = { s_fxh[sx0], s_fxh[sx1] };
        const float fxl_[2] = { s_fxl[sx0], s_fxl[sx1] };
        #pragma unroll
        for (int ys = 0; ys < 2; ++ys) {
            #pragma unroll
            for (int xs = 0; xs < 2; ++xs) {
                const int o = (ys*2 + xs) * 4;
                wt[o+0] = fyh_[ys] * fxh_[xs] * 0.25f;
                wt[o+1] = fyh_[ys] * fxl_[xs] * 0.25f;
                wt[o+2] = fyl_[ys] * fxh_[xs] * 0.25f;
                wt[o+3] = fyl_[ys] * fxl_[xs] * 0.25f;
            }
        }
    }

    const int bidx = k / NBOX_PER_B;
    const size_t plane = (size_t)H * (size_t)W;
    const float* fbase = fptr + ((size_t)bidx * C_TOT + (size_t)cg * CG) * plane
                              + (size_t)ymin * W + xmin;
    const float* g0 = fbase;
    const float* g1 = fbase + plane;
    const float* g2 = fbase + 2*plane;
    const float* g3 = fbase + 3*plane;
    for (int i = tid; i < nelem; i += NTHREADS) {
        const int r  = (int)(((float)i + 0.5f) * rcpc);
        const int cc = i - r * ncols;
        const int go = r * W + cc;
        const int di = r * stridep + cc;
        float4 v;
        v.x = g0[go]; v.y = g1[go]; v.z = g2[go]; v.w = g3[go];
        if (di < 1280) s_patch[di] = v;
    }
    __syncthreads();

    if (active) {
        float4 acc = {0.0f, 0.0f, 0.0f, 0.0f};
        #pragma unroll
        for (int ys = 0; ys < 2; ++ys) {
            const int rbase = (ys == 0) ? rb0 : rb1;
            #pragma unroll
            for (int xs = 0; xs < 2; ++xs) {
                const int base = rbase + ((xs == 0) ? cbase0 : cbase1);
                const float4 v00 = s_patch[base];
                const float4 v01 = s_patch[base + 1];
                const float4 v10 = s_patch[base + stridep];
                const float4 v11 = s_patch[base + stridep + 1];
                const int o = (ys*2 + xs) * 4;
                const float w00 = wt[o+0], w01 = wt[o+1], w10 = wt[o+2], w11 = wt[o+3];
                acc.x += w00*v00.x + w01*v01.x + w10*v10.x + w11*v11.x;
                acc.y += w00*v00.y + w01*v01.y + w10*v10.y + w11*v11.y;
                acc.z += w00*v00.z + w01*v01.z + w10*v10.z + w11*v11.z;
                acc.w += w00*v00.w + w01*v01.w + w10*v10.w + w11*v11.w;
            }
        }
        float* ob = out + ((size_t)k * C_TOT + (size_t)cg * CG) * NPIX + tid;
        ob[0*NPIX] = acc.x;
        ob[1*NPIX] = acc.y;
        ob[2*NPIX] = acc.z;
        ob[3*NPIX] = acc.w;
    }
}

extern "C" void kernel_launch(void* const* d_in, const int* in_sizes, int n_in,
                              void* d_out, int out_size, void* d_ws, size_t ws_size,
                              hipStream_t stream) {
    const float* f0    = (const float*)d_in[0];
    const float* f1    = (const float*)d_in[1];
    const float* f2    = (const float*)d_in[2];
    const float* f3    = (const float*)d_in[3];
    const float* boxes = (const float*)d_in[4];
    float* out = (float*)d_out;

    if (ws_size >= (size_t)WS_NEEDED) {
        char* ws = (char*)d_ws;
        int*    metaW = (int*)   (ws + META_OFF);
        int4*   idxW  = (int4*)  (ws + IDX_OFF);
        float4* wyW   = (float4*)(ws + WY_OFF);
        float4* wxW   = (float4*)(ws + WX_OFF);

        roi_setup_kernel<<<NROI, NTHREADS, 0, stream>>>(boxes, metaW, idxW, wyW, wxW);
        dim3 grid(C_TOT / CG, NROI);   // 64 groups x 256 rois (same-roi adjacent)
        roi_align_v2_kernel<<<grid, NTHREADS, 0, stream>>>(
            f0, f1, f2, f3, metaW, idxW, wyW, wxW, out);
    } else {
        dim3 grid(NROI, C_TOT / CG);
        roi_align_fpn_kernel<<<grid, NTHREADS, 0, stream>>>(f0, f1, f2, f3, boxes, out);
    }
}

// Round 10
// 40.718 us; speedup vs baseline: 1.2524x; 1.2524x over previous
//
#include <hip/hip_runtime.h>
#include <math.h>

#define OUT 14
#define RATIO 2
#define NS (OUT*RATIO)      // 28 sample positions per axis
#define NPIX (OUT*OUT)      // 196
#define C_TOT 256
#define CG 4                // channels per block (float4 interleave)
#define NBOX_PER_B 128
#define NTHREADS 256
#define PATCH_CAP 1280      // float4 slots; worst-case patch ~1043 (level-0 wide-thin)
#define NROI 256

// ---------------------------------------------------------------------
// torchvision roi_align axis prep (must match reference op-for-op):
// valid = (c>-1)&(c<L); c=clip(c,0,L-1); lo=clip(floor(c),0,L-2); fr=c-lo
// ---------------------------------------------------------------------
__device__ __forceinline__ void prep_axis(float c, int L, int& lo, float& fh, float& fl)
{
    const bool  v  = (c > -1.0f) && (c < (float)L);
    const float cc = fminf(fmaxf(c, 0.0f), (float)(L - 1));
    const float fb = fminf(fmaxf(floorf(cc), 0.0f), (float)(L - 2));
    const float fr = cc - fb;
    lo = (int)fb;
    fl = v ? fr        : 0.0f;
    fh = v ? 1.0f - fr : 0.0f;
}

// floor index only (for patch extent; cheap form of prep_axis)
__device__ __forceinline__ int axis_lo(float c, int L)
{
    const float cc = fminf(fmaxf(c, 0.0f), (float)(L - 1));
    return (int)fminf(fmaxf(floorf(cc), 0.0f), (float)(L - 2));
}

// =====================================================================
// Fused single kernel: grid (64 groups, 256 rois). Per block:
//  1. ~50 redundant VALU ops: box -> level, patch extent (no barrier)
//  2. per-pixel sample floors/weights in REGISTERS (tid<196, ~60 VALU)
//  3. stage patch (4 channels float4-interleaved, coalesced)  [R5 core]
//  4. one barrier, 16 x ds_read_b128 taps, 64 FMA, coalesced stores
// No setup kernel, no workspace, no record loads, LDS = 20480 B.
// =====================================================================
__global__ __launch_bounds__(NTHREADS)
void roi_align_fused_kernel(const float* __restrict__ f0,
                            const float* __restrict__ f1,
                            const float* __restrict__ f2,
                            const float* __restrict__ f3,
                            const float* __restrict__ boxes,
                            float* __restrict__ out)
{
    const int cg  = blockIdx.x;   // channel group, 0..63
    const int k   = blockIdx.y;   // roi, 0..255
    const int tid = threadIdx.x;

    __shared__ float4 s_patch[PATCH_CAP];   // 20480 B exactly

    // ---- per-roi params (uniform; computed redundantly, no LDS) ----
    const float bx1 = boxes[k*4+0];
    const float by1 = boxes[k*4+1];
    const float bx2 = boxes[k*4+2];
    const float by2 = boxes[k*4+3];

    const float wbox = bx2 - bx1;
    const float hbox = by2 - by1;
    const float sdim = sqrtf(wbox * hbox);
    float lvlf = floorf(4.0f + log2f(sdim / 224.0f + 1e-6f));
    lvlf = fminf(fmaxf(lvlf, 2.0f), 5.0f);
    const int lidx = (int)lvlf - 2;   // 0..3

    const float* fptr;
    int H, W;
    float scale;
    if      (lidx == 0) { fptr = f0; H = 200; W = 200; scale = 0.25f;    }
    else if (lidx == 1) { fptr = f1; H = 100; W = 100; scale = 0.125f;   }
    else if (lidx == 2) { fptr = f2; H = 50;  W = 50;  scale = 0.0625f;  }
    else                { fptr = f3; H = 25;  W = 25;  scale = 0.03125f; }

    const float x1 = bx1 * scale;
    const float y1 = by1 * scale;
    const float x2 = bx2 * scale;
    const float y2 = by2 * scale;
    const float rw = fmaxf(x2 - x1, 1.0f);
    const float rh = fmaxf(y2 - y1, 1.0f);
    const float bw = rw / (float)OUT;
    const float bh = rh / (float)OUT;

    // ---- patch extent from first/last sample (tables are monotone) ----
    const float off0  = 0.25f;                 // (0 + 0.5)/2
    const float offL  = ((float)(NS-1) + 0.5f) * 0.5f;
    const int ymin  = axis_lo(y1 + bh * off0, H);
    const int xmin  = axis_lo(x1 + bw * off0, W);
    const int nrows = axis_lo(y1 + bh * offL, H) + 2 - ymin;
    const int ncols = axis_lo(x1 + bw * offL, W) + 2 - xmin;
    const int padded  = ncols | 1;
    const int stridep = (nrows * padded <= PATCH_CAP) ? padded : ncols;
    const int nelem   = nrows * ncols;
    const float rcpc  = 1.0f / (float)ncols;

    // ---- per-pixel tap state in registers (no LDS tables, no barrier) ----
    const bool active = (tid < NPIX);
    int rb0 = 0, rb1 = 0, cb0 = 0, cb1 = 0;
    float4 wy = {0,0,0,0};   // y weights * 0.25
    float4 wx = {0,0,0,0};   // x weights
    if (active) {
        const int ph = tid / OUT;
        const int pw = tid - ph * OUT;
        int lo; float fh, fl;
        // y samples 2*ph, 2*ph+1
        prep_axis(y1 + bh * (((float)(2*ph)   + 0.5f) * 0.5f), H, lo, fh, fl);
        rb0 = (lo - ymin) * stridep; wy.x = fh * 0.25f; wy.y = fl * 0.25f;
        prep_axis(y1 + bh * (((float)(2*ph+1) + 0.5f) * 0.5f), H, lo, fh, fl);
        rb1 = (lo - ymin) * stridep; wy.z = fh * 0.25f; wy.w = fl * 0.25f;
        // x samples 2*pw, 2*pw+1
        prep_axis(x1 + bw * (((float)(2*pw)   + 0.5f) * 0.5f), W, lo, fh, fl);
        cb0 = lo - xmin; wx.x = fh; wx.y = fl;
        prep_axis(x1 + bw * (((float)(2*pw+1) + 0.5f) * 0.5f), W, lo, fh, fl);
        cb1 = lo - xmin; wx.z = fh; wx.w = fl;
    }

    // ---- stage patch: 4 channels interleaved, coalesced (R5 core) ----
    const size_t plane = (size_t)H * (size_t)W;
    const float* fbase = fptr
        + ((size_t)(k / NBOX_PER_B) * C_TOT + (size_t)cg * CG) * plane
        + (size_t)ymin * W + xmin;
    const float* g0 = fbase;
    const float* g1 = fbase +   plane;
    const float* g2 = fbase + 2*plane;
    const float* g3 = fbase + 3*plane;
    for (int i = tid; i < nelem; i += NTHREADS) {
        const int r  = (int)(((float)i + 0.5f) * rcpc);   // exact floor (margin >> err)
        const int cc = i - r * ncols;
        const int go = r * W + cc;
        const int di = r * stridep + cc;
        float4 v;
        v.x = g0[go]; v.y = g1[go]; v.z = g2[go]; v.w = g3[go];
        if (di < PATCH_CAP) s_patch[di] = v;
    }
    __syncthreads();

    // ---- bilinear: 16 x ds_read_b128, 64 FMA per pixel (4 channels) ----
    if (active) {
        float4 acc = {0.0f, 0.0f, 0.0f, 0.0f};
        #pragma unroll
        for (int ys = 0; ys < 2; ++ys) {
            const int   rb = ys ? rb1 : rb0;
            const float yh = ys ? wy.z : wy.x;
            const float yl = ys ? wy.w : wy.y;
            #pragma unroll
            for (int xs = 0; xs < 2; ++xs) {
                const int base = rb + (xs ? cb1 : cb0);
                const float xh = xs ? wx.z : wx.x;
                const float xl = xs ? wx.w : wx.y;
                const float w00 = yh*xh, w01 = yh*xl, w10 = yl*xh, w11 = yl*xl;
                const float4 v00 = s_patch[base];
                const float4 v01 = s_patch[base + 1];
                const float4 v10 = s_patch[base + stridep];
                const float4 v11 = s_patch[base + stridep + 1];
                acc.x += w00*v00.x + w01*v01.x + w10*v10.x + w11*v11.x;
                acc.y += w00*v00.y + w01*v01.y + w10*v10.y + w11*v11.y;
                acc.z += w00*v00.z + w01*v01.z + w10*v10.z + w11*v11.z;
                acc.w += w00*v00.w + w01*v01.w + w10*v10.w + w11*v11.w;
            }
        }
        float* ob = out + ((size_t)k * C_TOT + (size_t)cg * CG) * NPIX + tid;
        ob[0*NPIX] = acc.x;
        ob[1*NPIX] = acc.y;
        ob[2*NPIX] = acc.z;
        ob[3*NPIX] = acc.w;
    }
}

extern "C" void kernel_launch(void* const* d_in, const int* in_sizes, int n_in,
                              void* d_out, int out_size, void* d_ws, size_t ws_size,
                              hipStream_t stream) {
    const float* f0    = (const float*)d_in[0];
    const float* f1    = (const float*)d_in[1];
    const float* f2    = (const float*)d_in[2];
    const float* f3    = (const float*)d_in[3];
    const float* boxes = (const float*)d_in[4];
    float* out = (float*)d_out;

    dim3 grid(C_TOT / CG, NROI);   // 64 groups x 256 rois (same-roi adjacent)
    roi_align_fused_kernel<<<grid, NTHREADS, 0, stream>>>(f0, f1, f2, f3, boxes, out);
}

// Round 11
// 37.375 us; speedup vs baseline: 1.3645x; 1.0894x over previous
//
#include <hip/hip_runtime.h>
#include <math.h>

#define OUT 14
#define RATIO 2
#define NS (OUT*RATIO)      // 28 sample positions per axis
#define NPIX (OUT*OUT)      // 196
#define C_TOT 256
#define CG 4                // channels per group (float4 interleave)
#define GPB 2               // groups per block (prologue amortization)
#define NCHUNK (C_TOT/(CG*GPB))   // 32
#define NBOX_PER_B 128
#define NTHREADS 256
#define PATCH_CAP 1280      // float4 slots; worst-case patch ~1043
#define MAXIT 5             // ceil(PATCH_CAP/NTHREADS)
#define NROI 256

// ---------------------------------------------------------------------
// torchvision roi_align axis prep (must match reference op-for-op):
// valid = (c>-1)&(c<L); c=clip(c,0,L-1); lo=clip(floor(c),0,L-2); fr=c-lo
// ---------------------------------------------------------------------
__device__ __forceinline__ void prep_axis(float c, int L, int& lo, float& fh, float& fl)
{
    const bool  v  = (c > -1.0f) && (c < (float)L);
    const float cc = fminf(fmaxf(c, 0.0f), (float)(L - 1));
    const float fb = fminf(fmaxf(floorf(cc), 0.0f), (float)(L - 2));
    const float fr = cc - fb;
    lo = (int)fb;
    fl = v ? fr        : 0.0f;
    fh = v ? 1.0f - fr : 0.0f;
}

__device__ __forceinline__ int axis_lo(float c, int L)
{
    const float cc = fminf(fmaxf(c, 0.0f), (float)(L - 1));
    return (int)fminf(fmaxf(floorf(cc), 0.0f), (float)(L - 2));
}

// =====================================================================
// Fused amortized kernel: grid (32 chunks, 256 rois). Each block owns
// GPB=2 four-channel groups of one roi. The roi-dependent VALU work
// (level transcendentals, patch extent, per-pixel sample prep, staging
// coordinates) is computed ONCE and reused for both groups; only the
// staging loads + tap/FMA phase repeat. LDS stays 20480 B (one patch
// buffer, reused across groups with barriers).
// =====================================================================
__global__ __launch_bounds__(NTHREADS)
void roi_align_fused2_kernel(const float* __restrict__ f0,
                             const float* __restrict__ f1,
                             const float* __restrict__ f2,
                             const float* __restrict__ f3,
                             const float* __restrict__ boxes,
                             float* __restrict__ out)
{
    const int chunk = blockIdx.x;   // 0..31
    const int k     = blockIdx.y;   // roi, 0..255
    const int tid   = threadIdx.x;

    __shared__ float4 s_patch[PATCH_CAP];   // 20480 B exactly

    // ---- per-roi params (uniform; computed redundantly, no LDS) ----
    const float bx1 = boxes[k*4+0];
    const float by1 = boxes[k*4+1];
    const float bx2 = boxes[k*4+2];
    const float by2 = boxes[k*4+3];

    const float wbox = bx2 - bx1;
    const float hbox = by2 - by1;
    const float sdim = sqrtf(wbox * hbox);
    float lvlf = floorf(4.0f + log2f(sdim / 224.0f + 1e-6f));
    lvlf = fminf(fmaxf(lvlf, 2.0f), 5.0f);
    const int lidx = (int)lvlf - 2;   // 0..3

    const float* fptr;
    int H, W;
    float scale;
    if      (lidx == 0) { fptr = f0; H = 200; W = 200; scale = 0.25f;    }
    else if (lidx == 1) { fptr = f1; H = 100; W = 100; scale = 0.125f;   }
    else if (lidx == 2) { fptr = f2; H = 50;  W = 50;  scale = 0.0625f;  }
    else                { fptr = f3; H = 25;  W = 25;  scale = 0.03125f; }

    const float x1 = bx1 * scale;
    const float y1 = by1 * scale;
    const float x2 = bx2 * scale;
    const float y2 = by2 * scale;
    const float rw = fmaxf(x2 - x1, 1.0f);
    const float rh = fmaxf(y2 - y1, 1.0f);
    const float bw = rw / (float)OUT;
    const float bh = rh / (float)OUT;

    // ---- patch extent from first/last sample (monotone tables) ----
    const float off0  = 0.25f;
    const float offL  = ((float)(NS-1) + 0.5f) * 0.5f;
    const int ymin  = axis_lo(y1 + bh * off0, H);
    const int xmin  = axis_lo(x1 + bw * off0, W);
    const int nrows = axis_lo(y1 + bh * offL, H) + 2 - ymin;
    const int ncols = axis_lo(x1 + bw * offL, W) + 2 - xmin;
    const int padded  = ncols | 1;
    const int stridep = (nrows * padded <= PATCH_CAP) ? padded : ncols;
    const int nelem   = nrows * ncols;
    const float rcpc  = 1.0f / (float)ncols;

    // ---- per-pixel tap state in registers (computed once) ----
    const bool active = (tid < NPIX);
    int rb0 = 0, rb1 = 0, cb0 = 0, cb1 = 0;
    float4 wy = {0,0,0,0};   // y weights * 0.25
    float4 wx = {0,0,0,0};   // x weights
    if (active) {
        const int ph = tid / OUT;
        const int pw = tid - ph * OUT;
        int lo; float fh, fl;
        prep_axis(y1 + bh * (((float)(2*ph)   + 0.5f) * 0.5f), H, lo, fh, fl);
        rb0 = (lo - ymin) * stridep; wy.x = fh * 0.25f; wy.y = fl * 0.25f;
        prep_axis(y1 + bh * (((float)(2*ph+1) + 0.5f) * 0.5f), H, lo, fh, fl);
        rb1 = (lo - ymin) * stridep; wy.z = fh * 0.25f; wy.w = fl * 0.25f;
        prep_axis(x1 + bw * (((float)(2*pw)   + 0.5f) * 0.5f), W, lo, fh, fl);
        cb0 = lo - xmin; wx.x = fh; wx.y = fl;
        prep_axis(x1 + bw * (((float)(2*pw+1) + 0.5f) * 0.5f), W, lo, fh, fl);
        cb1 = lo - xmin; wx.z = fh; wx.w = fl;
    }

    // ---- staging coordinates (computed once, reused for both groups) ----
    const size_t plane = (size_t)H * (size_t)W;
    int go_[MAXIT], di_[MAXIT];
    #pragma unroll
    for (int t = 0; t < MAXIT; ++t) {
        const int i  = t*NTHREADS + tid;
        const int r  = (int)(((float)i + 0.5f) * rcpc);   // exact floor
        const int cc = i - r * ncols;
        go_[t] = r * W + cc;
        di_[t] = (i < nelem && r * stridep + cc < PATCH_CAP) ? (r * stridep + cc) : -1;
    }

    const float* fbase = fptr
        + ((size_t)(k / NBOX_PER_B) * C_TOT + (size_t)chunk * (GPB*CG)) * plane
        + (size_t)ymin * W + xmin;
    float* outk = out + ((size_t)k * C_TOT + (size_t)chunk * (GPB*CG)) * NPIX;

    #pragma unroll
    for (int g = 0; g < GPB; ++g) {
        // ---- stage group g: 4 channels interleaved, coalesced ----
        const float* g0 = fbase + (size_t)(g*CG) * plane;
        const float* g1 = g0 +   plane;
        const float* g2 = g0 + 2*plane;
        const float* g3 = g0 + 3*plane;
        #pragma unroll
        for (int t = 0; t < MAXIT; ++t) {
            if (di_[t] >= 0) {
                const int go = go_[t];
                float4 v;
                v.x = g0[go]; v.y = g1[go]; v.z = g2[go]; v.w = g3[go];
                s_patch[di_[t]] = v;
            }
        }
        __syncthreads();

        // ---- bilinear: 16 x ds_read_b128, 64 FMA per pixel ----
        if (active) {
            float4 acc = {0.0f, 0.0f, 0.0f, 0.0f};
            #pragma unroll
            for (int ys = 0; ys < 2; ++ys) {
                const int   rb = ys ? rb1 : rb0;
                const float yh = ys ? wy.z : wy.x;
                const float yl = ys ? wy.w : wy.y;
                #pragma unroll
                for (int xs = 0; xs < 2; ++xs) {
                    const int base = rb + (xs ? cb1 : cb0);
                    const float xh = xs ? wx.z : wx.x;
                    const float xl = xs ? wx.w : wx.y;
                    const float w00 = yh*xh, w01 = yh*xl, w10 = yl*xh, w11 = yl*xl;
                    const float4 v00 = s_patch[base];
                    const float4 v01 = s_patch[base + 1];
                    const float4 v10 = s_patch[base + stridep];
                    const float4 v11 = s_patch[base + stridep + 1];
                    acc.x += w00*v00.x + w01*v01.x + w10*v10.x + w11*v11.x;
                    acc.y += w00*v00.y + w01*v01.y + w10*v10.y + w11*v11.y;
                    acc.z += w00*v00.z + w01*v01.z + w10*v10.z + w11*v11.z;
                    acc.w += w00*v00.w + w01*v01.w + w10*v10.w + w11*v11.w;
                }
            }
            float* ob = outk + (size_t)(g*CG) * NPIX + tid;
            ob[0*NPIX] = acc.x;
            ob[1*NPIX] = acc.y;
            ob[2*NPIX] = acc.z;
            ob[3*NPIX] = acc.w;
        }
        if (g + 1 < GPB) __syncthreads();
    }
}

extern "C" void kernel_launch(void* const* d_in, const int* in_sizes, int n_in,
                              void* d_out, int out_size, void* d_ws, size_t ws_size,
                              hipStream_t stream) {
    const float* f0    = (const float*)d_in[0];
    const float* f1    = (const float*)d_in[1];
    const float* f2    = (const float*)d_in[2];
    const float* f3    = (const float*)d_in[3];
    const float* boxes = (const float*)d_in[4];
    float* out = (float*)d_out;

    dim3 grid(NCHUNK, NROI);   // 32 chunks x 256 rois (same-roi adjacent)
    roi_align_fused2_kernel<<<grid, NTHREADS, 0, stream>>>(f0, f1, f2, f3, boxes, out);
}

// Round 12
// 37.218 us; speedup vs baseline: 1.3702x; 1.0042x over previous
//
#include <hip/hip_runtime.h>
#include <math.h>

#define OUT 14
#define RATIO 2
#define NS (OUT*RATIO)      // 28 sample positions per axis
#define NPIX (OUT*OUT)      // 196
#define C_TOT 256
#define CG 4                // channels per group (float4 interleave)
#define GPB 4               // groups per block (prologue amortization)
#define NCHUNK (C_TOT/(CG*GPB))   // 16
#define NBOX_PER_B 128
#define NTHREADS 256
#define PATCH_CAP 1280      // float4 slots; worst-case patch ~1043
#define MAXIT 5             // ceil(PATCH_CAP/NTHREADS)
#define NROI 256

// ---------------------------------------------------------------------
// torchvision roi_align axis prep (must match reference op-for-op):
// valid = (c>-1)&(c<L); c=clip(c,0,L-1); lo=clip(floor(c),0,L-2); fr=c-lo
// ---------------------------------------------------------------------
__device__ __forceinline__ void prep_axis(float c, int L, int& lo, float& fh, float& fl)
{
    const bool  v  = (c > -1.0f) && (c < (float)L);
    const float cc = fminf(fmaxf(c, 0.0f), (float)(L - 1));
    const float fb = fminf(fmaxf(floorf(cc), 0.0f), (float)(L - 2));
    const float fr = cc - fb;
    lo = (int)fb;
    fl = v ? fr        : 0.0f;
    fh = v ? 1.0f - fr : 0.0f;
}

__device__ __forceinline__ int axis_lo(float c, int L)
{
    const float cc = fminf(fmaxf(c, 0.0f), (float)(L - 1));
    return (int)fminf(fmaxf(floorf(cc), 0.0f), (float)(L - 2));
}

// =====================================================================
// Fused amortized kernel: grid (16 chunks, 256 rois). Each block owns
// GPB=4 four-channel groups of one roi. All roi-dependent VALU work
// (level transcendentals, patch extent, per-pixel sample prep, staging
// coordinates) is computed ONCE and reused for all groups; only the
// staging loads + tap/FMA phase repeat per group. LDS = 20480 B (one
// patch buffer, reused across groups with barriers).
// =====================================================================
__global__ __launch_bounds__(NTHREADS)
void roi_align_fused4_kernel(const float* __restrict__ f0,
                             const float* __restrict__ f1,
                             const float* __restrict__ f2,
                             const float* __restrict__ f3,
                             const float* __restrict__ boxes,
                             float* __restrict__ out)
{
    const int chunk = blockIdx.x;   // 0..15
    const int k     = blockIdx.y;   // roi, 0..255
    const int tid   = threadIdx.x;

    __shared__ float4 s_patch[PATCH_CAP];   // 20480 B exactly

    // ---- per-roi params (uniform; computed redundantly, no LDS) ----
    const float bx1 = boxes[k*4+0];
    const float by1 = boxes[k*4+1];
    const float bx2 = boxes[k*4+2];
    const float by2 = boxes[k*4+3];

    const float wbox = bx2 - bx1;
    const float hbox = by2 - by1;
    const float sdim = sqrtf(wbox * hbox);
    float lvlf = floorf(4.0f + log2f(sdim / 224.0f + 1e-6f));
    lvlf = fminf(fmaxf(lvlf, 2.0f), 5.0f);
    const int lidx = (int)lvlf - 2;   // 0..3

    const float* fptr;
    int H, W;
    float scale;
    if      (lidx == 0) { fptr = f0; H = 200; W = 200; scale = 0.25f;    }
    else if (lidx == 1) { fptr = f1; H = 100; W = 100; scale = 0.125f;   }
    else if (lidx == 2) { fptr = f2; H = 50;  W = 50;  scale = 0.0625f;  }
    else                { fptr = f3; H = 25;  W = 25;  scale = 0.03125f; }

    const float x1 = bx1 * scale;
    const float y1 = by1 * scale;
    const float x2 = bx2 * scale;
    const float y2 = by2 * scale;
    const float rw = fmaxf(x2 - x1, 1.0f);
    const float rh = fmaxf(y2 - y1, 1.0f);
    const float bw = rw / (float)OUT;
    const float bh = rh / (float)OUT;

    // ---- patch extent from first/last sample (monotone tables) ----
    const float off0  = 0.25f;
    const float offL  = ((float)(NS-1) + 0.5f) * 0.5f;
    const int ymin  = axis_lo(y1 + bh * off0, H);
    const int xmin  = axis_lo(x1 + bw * off0, W);
    const int nrows = axis_lo(y1 + bh * offL, H) + 2 - ymin;
    const int ncols = axis_lo(x1 + bw * offL, W) + 2 - xmin;
    const int padded  = ncols | 1;
    const int stridep = (nrows * padded <= PATCH_CAP) ? padded : ncols;
    const int nelem   = nrows * ncols;
    const float rcpc  = 1.0f / (float)ncols;

    // ---- per-pixel tap state in registers (computed once) ----
    const bool active = (tid < NPIX);
    int rb0 = 0, rb1 = 0, cb0 = 0, cb1 = 0;
    float4 wy = {0,0,0,0};   // y weights * 0.25
    float4 wx = {0,0,0,0};   // x weights
    if (active) {
        const int ph = tid / OUT;
        const int pw = tid - ph * OUT;
        int lo; float fh, fl;
        prep_axis(y1 + bh * (((float)(2*ph)   + 0.5f) * 0.5f), H, lo, fh, fl);
        rb0 = (lo - ymin) * stridep; wy.x = fh * 0.25f; wy.y = fl * 0.25f;
        prep_axis(y1 + bh * (((float)(2*ph+1) + 0.5f) * 0.5f), H, lo, fh, fl);
        rb1 = (lo - ymin) * stridep; wy.z = fh * 0.25f; wy.w = fl * 0.25f;
        prep_axis(x1 + bw * (((float)(2*pw)   + 0.5f) * 0.5f), W, lo, fh, fl);
        cb0 = lo - xmin; wx.x = fh; wx.y = fl;
        prep_axis(x1 + bw * (((float)(2*pw+1) + 0.5f) * 0.5f), W, lo, fh, fl);
        cb1 = lo - xmin; wx.z = fh; wx.w = fl;
    }

    // ---- staging coordinates (computed once, reused for all groups) ----
    const size_t plane = (size_t)H * (size_t)W;
    int go_[MAXIT], di_[MAXIT];
    #pragma unroll
    for (int t = 0; t < MAXIT; ++t) {
        const int i  = t*NTHREADS + tid;
        const int r  = (int)(((float)i + 0.5f) * rcpc);   // exact floor
        const int cc = i - r * ncols;
        go_[t] = r * W + cc;
        di_[t] = (i < nelem && r * stridep + cc < PATCH_CAP) ? (r * stridep + cc) : -1;
    }

    const float* fbase = fptr
        + ((size_t)(k / NBOX_PER_B) * C_TOT + (size_t)chunk * (GPB*CG)) * plane
        + (size_t)ymin * W + xmin;
    float* outk = out + ((size_t)k * C_TOT + (size_t)chunk * (GPB*CG)) * NPIX;

    #pragma unroll
    for (int g = 0; g < GPB; ++g) {
        // ---- stage group g: 4 channels interleaved, coalesced ----
        const float* g0 = fbase + (size_t)(g*CG) * plane;
        const float* g1 = g0 +   plane;
        const float* g2 = g0 + 2*plane;
        const float* g3 = g0 + 3*plane;
        #pragma unroll
        for (int t = 0; t < MAXIT; ++t) {
            if (di_[t] >= 0) {
                const int go = go_[t];
                float4 v;
                v.x = g0[go]; v.y = g1[go]; v.z = g2[go]; v.w = g3[go];
                s_patch[di_[t]] = v;
            }
        }
        __syncthreads();

        // ---- bilinear: 16 x ds_read_b128, 64 FMA per pixel ----
        if (active) {
            float4 acc = {0.0f, 0.0f, 0.0f, 0.0f};
            #pragma unroll
            for (int ys = 0; ys < 2; ++ys) {
                const int   rb = ys ? rb1 : rb0;
                const float yh = ys ? wy.z : wy.x;
                const float yl = ys ? wy.w : wy.y;
                #pragma unroll
                for (int xs = 0; xs < 2; ++xs) {
                    const int base = rb + (xs ? cb1 : cb0);
                    const float xh = xs ? wx.z : wx.x;
                    const float xl = xs ? wx.w : wx.y;
                    const float w00 = yh*xh, w01 = yh*xl, w10 = yl*xh, w11 = yl*xl;
                    const float4 v00 = s_patch[base];
                    const float4 v01 = s_patch[base + 1];
                    const float4 v10 = s_patch[base + stridep];
                    const float4 v11 = s_patch[base + stridep + 1];
                    acc.x += w00*v00.x + w01*v01.x + w10*v10.x + w11*v11.x;
                    acc.y += w00*v00.y + w01*v01.y + w10*v10.y + w11*v11.y;
                    acc.z += w00*v00.z + w01*v01.z + w10*v10.z + w11*v11.z;
                    acc.w += w00*v00.w + w01*v01.w + w10*v10.w + w11*v11.w;
                }
            }
            float* ob = outk + (size_t)(g*CG) * NPIX + tid;
            ob[0*NPIX] = acc.x;
            ob[1*NPIX] = acc.y;
            ob[2*NPIX] = acc.z;
            ob[3*NPIX] = acc.w;
        }
        if (g + 1 < GPB) __syncthreads();
    }
}

extern "C" void kernel_launch(void* const* d_in, const int* in_sizes, int n_in,
                              void* d_out, int out_size, void* d_ws, size_t ws_size,
                              hipStream_t stream) {
    const float* f0    = (const float*)d_in[0];
    const float* f1    = (const float*)d_in[1];
    const float* f2    = (const float*)d_in[2];
    const float* f3    = (const float*)d_in[3];
    const float* boxes = (const float*)d_in[4];
    float* out = (float*)d_out;

    dim3 grid(NCHUNK, NROI);   // 16 chunks x 256 rois (same-roi adjacent)
    roi_align_fused4_kernel<<<grid, NTHREADS, 0, stream>>>(f0, f1, f2, f3, boxes, out);
}